// Round 7
// baseline (187.085 us; speedup 1.0000x reference)
//
#include <hip/hip_runtime.h>

typedef __bf16 bf16x8 __attribute__((ext_vector_type(8)));
typedef float f32x4 __attribute__((ext_vector_type(4)));

constexpr int Bsz = 16;
constexpr int Nsz = 1024;
constexpr int Dsz = 256;
constexpr int Hsz = 4;
constexpr int HFsz = 256;
constexpr int BN = Bsz * Nsz;

__device__ __forceinline__ unsigned f2bf(float f) {   // RNE fp32->bf16 (finite in)
    unsigned u = __float_as_uint(f);
    return (u + 0x7FFFu + ((u >> 16) & 1u)) >> 16;
}

// ---------------------------------------------------------------------------
// Kernel 0: WbT[c][d] = bf16(W[d][c])  (transpose-convert, 256x256)
// ---------------------------------------------------------------------------
__global__ __launch_bounds__(256) void wcvt(const float* __restrict__ Wm,
                                            unsigned short* __restrict__ WbT) {
    const int t = threadIdx.x;
    const int c = blockIdx.x * 4 + (t >> 6);
    const int d0 = (t & 63) * 4;
    const float v0 = Wm[(size_t)(d0 + 0) * HFsz + c];
    const float v1 = Wm[(size_t)(d0 + 1) * HFsz + c];
    const float v2 = Wm[(size_t)(d0 + 2) * HFsz + c];
    const float v3 = Wm[(size_t)(d0 + 3) * HFsz + c];
    uint2 pk;
    pk.x = f2bf(v0) | (f2bf(v1) << 16);
    pk.y = f2bf(v2) | (f2bf(v3) << 16);
    *(uint2*)&WbT[(size_t)c * Dsz + d0] = pk;   // coalesced 512B/wave
}

// ---------------------------------------------------------------------------
// Kernel 1: hT = bf16(x @ W)^T via MFMA + fused e_src/e_dst (fp32 dots).
// (unchanged — verified correct, ~10 us)
// ---------------------------------------------------------------------------
__global__ __launch_bounds__(256) void gat_h_e3(
    const float* __restrict__ x,              // [BN][D]
    const unsigned short* __restrict__ WbT,   // [HF][D] bf16
    const float* __restrict__ a_src,          // [HF]
    const float* __restrict__ a_dst,          // [HF]
    unsigned short* __restrict__ hT,          // [B][HF][N] bf16
    float* __restrict__ esrcT,                // [B][H][N]
    float* __restrict__ edstT)                // [B][H][N]
{
    const int n0g = blockIdx.x * 32, b = n0g >> 10, n0 = n0g & 1023;
    const int t = threadIdx.x, lane = t & 63, w = t >> 6;
    const int m = lane & 15, q = lane >> 4;

    __shared__ alignas(16) unsigned short Lds[4 * 64 * 40];  // 10240 hw = 20 KB

    const float4* x4 = (const float4*)(x + (size_t)n0g * Dsz);
#pragma unroll
    for (int i = 0; i < 8; ++i) {
        const int f = t + 256 * i;             // 2048 float4 total
        const int row = f >> 6, d4 = (f & 63) * 4;
        const float4 xv = x4[f];
        uint2 pk;
        pk.x = f2bf(xv.x) | (f2bf(xv.y) << 16);
        pk.y = f2bf(xv.z) | (f2bf(xv.w) << 16);
        *(uint2*)&Lds[row * 264 + d4] = pk;
    }
    __syncthreads();

    const unsigned short* Ab = WbT + (size_t)(w * 64 + m) * Dsz + q * 8;
    f32x4 acc[4][2];
#pragma unroll
    for (int ht = 0; ht < 4; ++ht)
#pragma unroll
        for (int nt = 0; nt < 2; ++nt) acc[ht][nt] = (f32x4){0.f, 0.f, 0.f, 0.f};

#pragma unroll
    for (int kk = 0; kk < 8; ++kk) {
        const int k0 = kk * 32;
        const bf16x8 bfr0 = *(const bf16x8*)&Lds[(0 * 16 + m) * 264 + k0 + q * 8];
        const bf16x8 bfr1 = *(const bf16x8*)&Lds[(1 * 16 + m) * 264 + k0 + q * 8];
#pragma unroll
        for (int ht = 0; ht < 4; ++ht) {
            const bf16x8 afr = *(const bf16x8*)&Ab[ht * 16 * Dsz + k0];
            acc[ht][0] = __builtin_amdgcn_mfma_f32_16x16x32_bf16(afr, bfr0, acc[ht][0], 0, 0, 0);
            acc[ht][1] = __builtin_amdgcn_mfma_f32_16x16x32_bf16(afr, bfr1, acc[ht][1], 0, 0, 0);
        }
    }

    float ps0 = 0.f, ps1 = 0.f, pd0 = 0.f, pd1 = 0.f;
#pragma unroll
    for (int ht = 0; ht < 4; ++ht)
#pragma unroll
        for (int r = 0; r < 4; ++r) {
            const float as = a_src[w * 64 + ht * 16 + q * 4 + r];
            const float ad = a_dst[w * 64 + ht * 16 + q * 4 + r];
            ps0 += acc[ht][0][r] * as;  ps1 += acc[ht][1][r] * as;
            pd0 += acc[ht][0][r] * ad;  pd1 += acc[ht][1][r] * ad;
        }
    ps0 += __shfl_xor(ps0, 16, 64); ps0 += __shfl_xor(ps0, 32, 64);
    ps1 += __shfl_xor(ps1, 16, 64); ps1 += __shfl_xor(ps1, 32, 64);
    pd0 += __shfl_xor(pd0, 16, 64); pd0 += __shfl_xor(pd0, 32, 64);
    pd1 += __shfl_xor(pd1, 16, 64); pd1 += __shfl_xor(pd1, 32, 64);
    if (q == 0) {
        const size_t eb = (size_t)(b * Hsz + w) * Nsz + n0;
        esrcT[eb + m] = ps0;  esrcT[eb + 16 + m] = ps1;
        edstT[eb + m] = pd0;  edstT[eb + 16 + m] = pd1;
    }

    __syncthreads();   // xs dead; reuse LDS as hs[4][64][40]

#pragma unroll
    for (int ht = 0; ht < 4; ++ht)
#pragma unroll
        for (int r = 0; r < 4; ++r) {
            const int hf = ht * 16 + q * 4 + r;
            Lds[w * 2560 + hf * 40 + m]      = (unsigned short)f2bf(acc[ht][0][r]);
            Lds[w * 2560 + hf * 40 + 16 + m] = (unsigned short)f2bf(acc[ht][1][r]);
        }
#pragma unroll
    for (int s = 0; s < 4; ++s) {
        const int hf = s * 16 + (lane >> 2), ck = lane & 3;
        const bf16x8 hv = *(const bf16x8*)&Lds[w * 2560 + hf * 40 + ck * 8];
        *(bf16x8*)&hT[(size_t)(b * HFsz + w * 64 + hf) * Nsz + n0 + ck * 8] = hv;
    }
}

// ---------------------------------------------------------------------------
// Kernel 2 (v5): barrier-free single-wave attention, register-budgeted.
// __launch_bounds__(64,4): VGPR cap 128 = the occupancy the 4096-block grid
// actually delivers (16 blocks/CU) -> full prefetch set stays live.
// Lane (q,m): adj rows 4q..4q+3, j 4m..4m+3 as float4 (13 vmem/iter, was 25);
// P_s written as 4x ds_write_b64; denominator via ones-B MFMA.
// ---------------------------------------------------------------------------
__global__ __launch_bounds__(64, 4) void gat_attn5(
    const float* __restrict__ adj,          // [B][N][N]
    const unsigned short* __restrict__ hT,  // [B][HF][N] bf16
    const float* __restrict__ esrcT,        // [B][H][N]
    const float* __restrict__ edstT,        // [B][H][N]
    const float* __restrict__ bias,         // [HF]
    float* __restrict__ outp)               // [BN][HF]
{
    const int gid = blockIdx.x;
    const int b  = gid & 15;                 // xcd = gid%8 -> b%8
    const int w  = (gid >> 4) & 3;
    const int i0 = (gid >> 6) * 16;
    const int lane = threadIdx.x, m = lane & 15, q = lane >> 4;

    __shared__ alignas(16) unsigned short P_s[16][72];
    __shared__ alignas(16) float ots[16][68];

    const float* adjb = adj + (size_t)b * Nsz * Nsz + (size_t)i0 * Nsz;
    const float* esb  = esrcT + (size_t)(b * Hsz + w) * Nsz;
    const float* edb  = edstT + (size_t)(b * Hsz + w) * Nsz + i0;
    const unsigned short* hTb = hT + (size_t)(b * HFsz + w * 64 + m) * Nsz + q * 8;

    float edreg[4];
#pragma unroll
    for (int r = 0; r < 4; ++r) edreg[r] = edb[q * 4 + r];

    bf16x8 ones;
#pragma unroll
    for (int i = 0; i < 8; ++i)
        ((unsigned short*)&ones)[i] = 0x3F80;   // bf16 1.0

    float4 aA[4], aB[4], esA, esB;
#pragma unroll
    for (int r = 0; r < 4; ++r)
        aA[r] = *(const float4*)&adjb[(size_t)(q * 4 + r) * Nsz + 4 * m];
    esA = *(const float4*)&esb[4 * m];

    f32x4 acc[4];
#pragma unroll
    for (int nt = 0; nt < 4; ++nt) acc[nt] = (f32x4){0.f, 0.f, 0.f, 0.f};
    f32x4 acc5 = (f32x4){0.f, 0.f, 0.f, 0.f};

    auto body = [&](int jt, float4 (&ac)[4], float4& esc,
                    float4 (&an)[4], float4& esn) {
        const int j0 = jt * 64;
        // (1) bfrag loads (L2-hot), consumed at step (4)
        bf16x8 bfr[8];
#pragma unroll
        for (int kk = 0; kk < 2; ++kk)
#pragma unroll
            for (int nt = 0; nt < 4; ++nt)
                bfr[kk * 4 + nt] =
                    *(const bf16x8*)&hTb[(size_t)nt * 16 * Nsz + j0 + kk * 32];

        // (2) next-tile HBM/L3 prefetch (float4, coalesced 1KB/instr)
        const int jn = (jt < 15) ? j0 + 64 : j0;
#pragma unroll
        for (int r = 0; r < 4; ++r)
            an[r] = *(const float4*)&adjb[(size_t)(q * 4 + r) * Nsz + jn + 4 * m];
        esn = *(const float4*)&esb[jn + 4 * m];

        // (3) exp for 4 rows x 4 j -> packed b64 P_s writes
        const float ek[4] = {esc.x, esc.y, esc.z, esc.w};
#pragma unroll
        for (int r = 0; r < 4; ++r) {
            const float ak[4] = {ac[r].x, ac[r].y, ac[r].z, ac[r].w};
            unsigned pk[4];
#pragma unroll
            for (int k = 0; k < 4; ++k) {
                float v = edreg[r] + ek[k];
                v = fmaxf(v, 0.2f * v);            // LeakyReLU
                const float p = __expf(v);          // no-max softmax: |v| <~ 12
                unsigned u = __float_as_uint(p);
                u = (ak[k] > 0.5f) ? u : 0u;
                pk[k] = u >> 16;                    // trunc bf16 (num/den consistent)
            }
            *(uint2*)&P_s[q * 4 + r][4 * m] =
                make_uint2(pk[0] | (pk[1] << 16), pk[2] | (pk[3] << 16));
        }
        // (4) MFMA: 8 agg + 2 denominator (wave-private LDS, no barrier)
#pragma unroll
        for (int kk = 0; kk < 2; ++kk) {
            const bf16x8 afrag = *(const bf16x8*)&P_s[m][kk * 32 + q * 8];
#pragma unroll
            for (int nt = 0; nt < 4; ++nt)
                acc[nt] = __builtin_amdgcn_mfma_f32_16x16x32_bf16(
                    afrag, bfr[kk * 4 + nt], acc[nt], 0, 0, 0);
            acc5 = __builtin_amdgcn_mfma_f32_16x16x32_bf16(afrag, ones, acc5,
                                                           0, 0, 0);
        }
    };

    for (int jt = 0; jt < 16; jt += 2) {   // ping-pong: no register rotates
        body(jt, aA, esA, aB, esB);
        body(jt + 1, aB, esB, aA, esA);
    }

    // ---- epilogue: linv directly from acc5 (C-layout rows q*4+r) ----
    float linv[4];
#pragma unroll
    for (int r = 0; r < 4; ++r) linv[r] = 1.f / acc5[r];

#pragma unroll
    for (int nt = 0; nt < 4; ++nt)
#pragma unroll
        for (int r = 0; r < 4; ++r)
            ots[q * 4 + r][nt * 16 + m] = acc[nt][r] * linv[r];

    const float4 bias4 = *(const float4*)&bias[w * 64 + m * 4];
#pragma unroll
    for (int s = 0; s < 4; ++s) {
        const int row = s * 4 + q;
        float4 v = *(const float4*)&ots[row][m * 4];
        v.x += bias4.x; v.y += bias4.y; v.z += bias4.z; v.w += bias4.w;
        *(float4*)&outp[(size_t)(b * Nsz + i0 + row) * HFsz + w * 64 + m * 4] = v;
    }
}

// ---------------------------------------------------------------------------
extern "C" void kernel_launch(void* const* d_in, const int* in_sizes, int n_in,
                              void* d_out, int out_size, void* d_ws, size_t ws_size,
                              hipStream_t stream) {
    const float* x     = (const float*)d_in[0];
    const float* adj   = (const float*)d_in[1];
    const float* Wm    = (const float*)d_in[2];
    const float* a_src = (const float*)d_in[3];
    const float* a_dst = (const float*)d_in[4];
    const float* bias  = (const float*)d_in[5];
    float* outp = (float*)d_out;

    // ws: hT bf16 (8MB) | WbT bf16 (128KB) | esrcT (256KB) | edstT (256KB)
    unsigned short* hT  = (unsigned short*)d_ws;
    unsigned short* WbT = hT + (size_t)BN * HFsz;
    float* esrcT = (float*)(WbT + (size_t)HFsz * Dsz);
    float* edstT = esrcT + (size_t)Bsz * Hsz * Nsz;

    wcvt<<<dim3(64), dim3(256), 0, stream>>>(Wm, WbT);
    gat_h_e3<<<dim3(BN / 32), dim3(256), 0, stream>>>(x, WbT, a_src, a_dst,
                                                      hT, esrcT, edstT);
    gat_attn5<<<dim3(4096), dim3(64), 0, stream>>>(adj, hT, esrcT, edstT,
                                                   bias, outp);
}